// Round 1
// baseline (7884.333 us; speedup 1.0000x reference)
//
#include <hip/hip_runtime.h>
#include <math.h>
#include <stdint.h>
#include <stddef.h>

typedef unsigned short u16;
typedef unsigned int   u32;
typedef __attribute__((ext_vector_type(8))) short short8;   // bf16x8 MFMA frag (guide §3)
typedef __attribute__((ext_vector_type(4))) float f32x4;

#define DI __device__ __forceinline__

// ---------------- problem constants ----------------
static constexpr int Vv = 32000, Ee = 512, Hh = 1024, Zz = 256;
static constexpr int Bb = 64, Ss = 256, Tt = 64;
static constexpr int G3 = 3 * Hh;            // 3072

// ---------------- workspace layout (bytes) ----------------
static constexpr size_t SZ_W3    = (size_t)G3 * G3 * 2;        // 18,874,368 (tripled Whh)
static constexpr size_t OFF_WHHE3 = 0;
static constexpr size_t OFF_WHHD3 = OFF_WHHE3 + SZ_W3;
static constexpr size_t OFF_WIHE3 = OFF_WHHD3 + SZ_W3;
static constexpr size_t SZ_WIHE3 = (size_t)G3 * (3 * Ee) * 2;  // 9,437,184
static constexpr size_t OFF_WVOC  = OFF_WIHE3 + SZ_WIHE3;
static constexpr size_t SZ_WVOC  = (size_t)Vv * Hh * 2;        // 65,536,000
static constexpr size_t OFF_XS    = OFF_WVOC + SZ_WVOC;        // x' split (dead after gx GEMM)
static constexpr size_t SZ_XS    = (size_t)Ss * Bb * (3 * Ee) * 2; // 50,331,648
static constexpr size_t OFF_GX    = OFF_XS + SZ_XS;
static constexpr size_t SZ_GX    = (size_t)Ss * Bb * G3 * 4;   // 201,326,592
// overlay inside XS region (only used after gx GEMM has consumed XS):
static constexpr size_t OFF_HA0  = OFF_XS;
static constexpr size_t OFF_HA1  = OFF_HA0 + (size_t)Bb * G3 * 2;   // 393,216 each
static constexpr size_t OFF_H    = OFF_HA1 + (size_t)Bb * G3 * 2;
static constexpr size_t OFF_H2F  = OFF_H   + (size_t)Bb * Hh * 4;
static constexpr size_t OFF_H2B  = OFF_H2F + (size_t)Tt * Bb * Hh * 4;
static constexpr size_t OFF_GXD  = OFF_H2B + (size_t)Tt * Bb * Hh * 2;
static constexpr size_t OFF_HENC = OFF_GXD + 12288;
static constexpr size_t OFF_ZB   = OFF_HENC + (size_t)Bb * Zz * 4;
static constexpr size_t OFF_RM   = OFF_ZB + (size_t)Bb * Zz * 4;
static constexpr size_t OFF_SE   = OFF_RM + 16384;
static constexpr size_t OFF_LSE  = OFF_SE + 16384;
static constexpr size_t OFF_BV   = OFF_LSE + 16384;
static constexpr size_t OFF_BI   = OFF_BV + 16384;
static constexpr size_t OFF_CC   = OFF_BI + 16384;
static constexpr size_t OFF_CAND = OFF_CC + 16384;             // 4096*32 ints

// ---------------- small helpers ----------------
DI u16 f2bf(float f) {                       // f32 -> bf16 RNE
  u32 u = __float_as_uint(f);
  u32 r = (u + 0x7FFFu + ((u >> 16) & 1u)) >> 16;
  return (u16)r;
}
DI float bf2f(u16 h) { return __uint_as_float(((u32)h) << 16); }

DI f32x4 mfma16(short8 a, short8 b, f32x4 c) {
  return __builtin_amdgcn_mfma_f32_16x16x32_bf16(a, b, c, 0, 0, 0);
}
DI void llds16(const u16* g, u16* l) {       // async global->LDS, 16B/lane (guide §5)
  __builtin_amdgcn_global_load_lds(
      (const __attribute__((address_space(1))) u32*)g,
      (__attribute__((address_space(3))) u32*)l, 16, 0, 0);
}

// ---------------- utility kernels ----------------
__global__ void k_zero(u32* p, int n) {
  for (int i = blockIdx.x * 256 + threadIdx.x; i < n; i += gridDim.x * 256) p[i] = 0;
}

// W (rows x kin) f32 -> tripled bf16 [W_hi | W_hi | W_lo] (rows x 3kin)
__global__ void k_trip(const float* __restrict__ W, u16* __restrict__ W3, int rows, int kin) {
  int n = rows * kin;
  for (int i = blockIdx.x * 256 + threadIdx.x; i < n; i += gridDim.x * 256) {
    int rr = i / kin, k = i - rr * kin;
    float v = W[i];
    u16 hi = f2bf(v);
    u16 lo = f2bf(v - bf2f(hi));
    u16* o = W3 + (size_t)rr * (3 * kin);
    o[k] = hi; o[kin + k] = hi; o[2 * kin + k] = lo;
  }
}

__global__ void k_tobf(const float* __restrict__ W, u16* __restrict__ Wb, int n) {
  for (int i = blockIdx.x * 256 + threadIdx.x; i < n; i += gridDim.x * 256) Wb[i] = f2bf(W[i]);
}

// x' = gathered embeddings split as [x_hi | x_lo | x_hi]  (matches B' = [W_hi|W_hi|W_lo])
__global__ void k_xsplit(const int* __restrict__ inp, const float* __restrict__ emb,
                         u16* __restrict__ xs) {
  int n = Ss * Bb * Ee;
  for (int i = blockIdx.x * 256 + threadIdx.x; i < n; i += gridDim.x * 256) {
    int m = i >> 9, k = i & (Ee - 1);
    int tok = inp[m];
    float v = emb[(size_t)tok * Ee + k];
    u16 hi = f2bf(v);
    u16 lo = f2bf(v - bf2f(hi));
    u16* o = xs + (size_t)m * (3 * Ee);
    o[k] = hi; o[Ee + k] = lo; o[2 * Ee + k] = hi;
  }
}

// gxd[g] = emb_dec[EOS] . Wih_d[g] + bih_d[g]   (exact f32, once)
__global__ void k_gxd(const float* __restrict__ emb_dec, const float* __restrict__ Wih_d,
                      const float* __restrict__ bih_d, float* __restrict__ gxd) {
  int g = blockIdx.x * 256 + threadIdx.x;
  if (g >= G3) return;
  const float* er = emb_dec + 2 * Ee;        // EOS_ID = 2
  const float* wr = Wih_d + (size_t)g * Ee;
  float s = 0.f;
  for (int e = 0; e < Ee; e++) s += er[e] * wr[e];
  gxd[g] = s + bih_d[g];
}

// ---------------- generic GEMM: C[m][n] = sum_k A[m][k]*B[n][k] + bias[n] (f32 out) ----------------
// 128x128 tile, BK=32, 4 waves, 16x16x32 bf16 MFMA, global_load_lds staging (m97-style).
__global__ __launch_bounds__(256, 2) void gemm_bt(
    const u16* __restrict__ A, const u16* __restrict__ Bw, const float* __restrict__ bias,
    float* __restrict__ C, int M, int N, int K) {
  __shared__ __align__(16) u16 As[128 * 32];
  __shared__ __align__(16) u16 Bs[128 * 32];
  int tid = threadIdx.x;
  int wave = tid >> 6, lane = tid & 63;
  int wr = wave >> 1, wc = wave & 1;
  int m0 = blockIdx.y * 128, n0 = blockIdx.x * 128;
  f32x4 acc[4][4];
#pragma unroll
  for (int i = 0; i < 4; i++)
#pragma unroll
    for (int j = 0; j < 4; j++) acc[i][j] = (f32x4){0.f, 0.f, 0.f, 0.f};

  int lrow = lane >> 2, lcol = (lane & 3) * 8;
  int r15 = lane & 15, kk = (lane >> 4) * 8;

  for (int k0 = 0; k0 < K; k0 += 32) {
    __syncthreads();                          // protect LDS from prior reads
#pragma unroll
    for (int rch = 0; rch < 2; rch++) {
      int c = rch * 4 + wave;                 // 8 chunks of 16 rows
      int row = c * 16 + lrow;
      llds16(A  + (size_t)(m0 + row) * K + k0 + lcol, &As[c * 512]);
      llds16(Bw + (size_t)(n0 + row) * K + k0 + lcol, &Bs[c * 512]);
    }
    __syncthreads();                          // drains vmcnt -> data in LDS
    short8 af[4], bfv[4];
#pragma unroll
    for (int mi = 0; mi < 4; mi++)
      af[mi] = *(const short8*)&As[(wr * 64 + mi * 16 + r15) * 32 + kk];
#pragma unroll
    for (int ni = 0; ni < 4; ni++)
      bfv[ni] = *(const short8*)&Bs[(wc * 64 + ni * 16 + r15) * 32 + kk];
#pragma unroll
    for (int mi = 0; mi < 4; mi++)
#pragma unroll
      for (int ni = 0; ni < 4; ni++) acc[mi][ni] = mfma16(af[mi], bfv[ni], acc[mi][ni]);
  }
#pragma unroll
  for (int mi = 0; mi < 4; mi++)
#pragma unroll
    for (int ni = 0; ni < 4; ni++) {
      int col = n0 + wc * 64 + ni * 16 + r15;
      float bs = bias[col];
#pragma unroll
      for (int i = 0; i < 4; i++) {
        int row = m0 + wr * 64 + mi * 16 + (lane >> 4) * 4 + i;
        C[(size_t)row * N + col] = acc[mi][ni][i] + bs;
      }
    }
}

// ---------------- one GRU step (tripled-K MFMA + fused gates) ----------------
// grid 128: wg&1 = m-half (32 batch rows), wg>>1 = j-slice (16 hidden dims -> 48 gate rows)
template <int DEC>
__global__ __launch_bounds__(256, 2) void k_step(
    const u16* __restrict__ W3, const float* __restrict__ bhh, const float* __restrict__ gxp,
    const u16* __restrict__ hAin, u16* __restrict__ hAout, float* __restrict__ h,
    float* __restrict__ h2f, u16* __restrict__ h2b) {
  __shared__ float Cred[4][32][48];
  int tid = threadIdx.x, wave = tid >> 6, lane = tid & 63;
  int wg = blockIdx.x;
  int mh = wg & 1;
  int j0 = (wg >> 1) * 16;
  int kbase = wave * 768;                     // waves split K=3072 by 4
  int kk = (lane >> 4) * 8, r15 = lane & 15;

  f32x4 acc[2][3];
#pragma unroll
  for (int i = 0; i < 2; i++)
#pragma unroll
    for (int j = 0; j < 3; j++) acc[i][j] = (f32x4){0.f, 0.f, 0.f, 0.f};

  const u16* Ab = hAin + (size_t)(mh * 32 + r15) * G3 + kbase + kk;
  const u16* Bb0 = W3 + (size_t)(j0 + r15) * G3 + kbase + kk;
#pragma unroll 4
  for (int ki = 0; ki < 24; ki++) {
    int ko = ki * 32;
    short8 a0 = *(const short8*)(Ab + ko);
    short8 a1 = *(const short8*)(Ab + (size_t)16 * G3 + ko);
    short8 b0 = *(const short8*)(Bb0 + ko);
    short8 b1 = *(const short8*)(Bb0 + (size_t)Hh * G3 + ko);
    short8 b2 = *(const short8*)(Bb0 + (size_t)2 * Hh * G3 + ko);
    acc[0][0] = mfma16(a0, b0, acc[0][0]);
    acc[0][1] = mfma16(a0, b1, acc[0][1]);
    acc[0][2] = mfma16(a0, b2, acc[0][2]);
    acc[1][0] = mfma16(a1, b0, acc[1][0]);
    acc[1][1] = mfma16(a1, b1, acc[1][1]);
    acc[1][2] = mfma16(a1, b2, acc[1][2]);
  }
#pragma unroll
  for (int mi = 0; mi < 2; mi++)
#pragma unroll
    for (int nf = 0; nf < 3; nf++)
#pragma unroll
      for (int i = 0; i < 4; i++)
        Cred[wave][mi * 16 + (lane >> 4) * 4 + i][nf * 16 + r15] = acc[mi][nf][i];
  __syncthreads();

#pragma unroll
  for (int e = 0; e < 2; e++) {
    int p = tid + e * 256;                    // 512 (b,j) pairs
    int b = p >> 4, jc = p & 15;
    int bg = mh * 32 + b;
    int j = j0 + jc;
    float hgr = Cred[0][b][jc]      + Cred[1][b][jc]      + Cred[2][b][jc]      + Cred[3][b][jc];
    float hgz = Cred[0][b][16 + jc] + Cred[1][b][16 + jc] + Cred[2][b][16 + jc] + Cred[3][b][16 + jc];
    float hgn = Cred[0][b][32 + jc] + Cred[1][b][32 + jc] + Cred[2][b][32 + jc] + Cred[3][b][32 + jc];
    hgr += bhh[j]; hgz += bhh[Hh + j]; hgn += bhh[2 * Hh + j];
    float xr, xz, xn;
    if (DEC) { xr = gxp[j]; xz = gxp[Hh + j]; xn = gxp[2 * Hh + j]; }
    else {
      const float* gr = gxp + (size_t)bg * G3;
      xr = gr[j]; xz = gr[Hh + j]; xn = gr[2 * Hh + j];
    }
    float rg = 1.0f / (1.0f + expf(-(xr + hgr)));
    float zg = 1.0f / (1.0f + expf(-(xz + hgz)));
    float ng = tanhf(xn + rg * hgn);
    float hold = h[(size_t)bg * Hh + j];
    float hn = (1.0f - zg) * ng + zg * hold;
    h[(size_t)bg * Hh + j] = hn;
    u16 hi = f2bf(hn);
    u16 lo = f2bf(hn - bf2f(hi));
    u16* oa = hAout + (size_t)bg * G3;
    oa[j] = hi; oa[Hh + j] = lo; oa[2 * Hh + j] = hi;
    if (DEC) {
      h2f[(size_t)bg * Hh + j] = hn;
      h2b[(size_t)bg * Hh + j] = hi;
    }
  }
}

// ---------------- heads (exact f32) ----------------
__global__ __launch_bounds__(256, 2) void k_head1(const float* __restrict__ h,
    const float* __restrict__ Wenc, const float* __restrict__ benc, float* __restrict__ henc) {
  int b = blockIdx.x;
  __shared__ float hs[Hh];
  for (int k = threadIdx.x; k < Hh; k += 256) hs[k] = h[(size_t)b * Hh + k];
  __syncthreads();
  int q = threadIdx.x;
  const float* wrw = Wenc + (size_t)q * Hh;
  float s = 0.f;
  for (int k = 0; k < Hh; k++) s += hs[k] * wrw[k];
  henc[b * Zz + q] = s + benc[q];
}

__global__ __launch_bounds__(256, 2) void k_head2(const float* __restrict__ henc,
    const float* __restrict__ Wloc, const float* __restrict__ bloc,
    const float* __restrict__ Wsc, const float* __restrict__ bsc,
    const float* __restrict__ eps, float* __restrict__ outLoc, float* __restrict__ outSc,
    float* __restrict__ zb) {
  int b = blockIdx.x;
  __shared__ float hs[Zz];
  if (threadIdx.x < Zz) hs[threadIdx.x] = henc[b * Zz + threadIdx.x];
  __syncthreads();
  int q = threadIdx.x;
  const float* wl = Wloc + (size_t)q * Zz;
  const float* wsp = Wsc + (size_t)q * Zz;
  float sl = 0.f, ssum = 0.f;
  for (int k = 0; k < Zz; k++) { sl += hs[k] * wl[k]; ssum += hs[k] * wsp[k]; }
  sl += bloc[q]; ssum += bsc[q];
  float sp = fmaxf(ssum, 0.f) + log1pf(expf(-fabsf(ssum)));  // softplus, stable
  float zv = sl + eps[b * Zz + q] * expf(0.5f * sp);
  outLoc[b * Zz + q] = sl;
  outSc[b * Zz + q] = sp;
  zb[b * Zz + q] = zv;
}

__global__ __launch_bounds__(256, 2) void k_head3(const float* __restrict__ zb,
    const float* __restrict__ Wdec, const float* __restrict__ bdec,
    float* __restrict__ h, u16* __restrict__ hA0) {
  int b = blockIdx.x;
  __shared__ float zs[Zz];
  if (threadIdx.x < Zz) zs[threadIdx.x] = zb[b * Zz + threadIdx.x];
  __syncthreads();
  for (int j = threadIdx.x; j < Hh; j += 256) {
    const float* wrw = Wdec + (size_t)j * Zz;
    float s = 0.f;
    for (int k = 0; k < Zz; k++) s += zs[k] * wrw[k];
    s += bdec[j];
    h[(size_t)b * Hh + j] = s;
    u16 hi = f2bf(s);
    u16 lo = f2bf(s - bf2f(hi));
    u16* oa = hA0 + (size_t)b * G3;
    oa[j] = hi; oa[Hh + j] = lo; oa[2 * Hh + j] = hi;
  }
}

// ---------------- row reduce: max, sumexp, candidates ----------------
__global__ __launch_bounds__(256, 2) void k_rowred(const float* __restrict__ logits,
    float* __restrict__ rowmax, float* __restrict__ sumexp, int* __restrict__ ccnt,
    int* __restrict__ cand) {
  int r = blockIdx.x;
  const float* row = logits + (size_t)r * Vv;
  __shared__ float red[4];
  __shared__ float srm;
  __shared__ int lcnt;
  __shared__ int lcand[32];
  int tid = threadIdx.x, wave = tid >> 6, lane = tid & 63;
  if (tid == 0) lcnt = 0;
  float m = -3.0e38f;
  for (int c = tid * 4; c < Vv; c += 1024) {
    f32x4 v = *(const f32x4*)(row + c);
    m = fmaxf(fmaxf(fmaxf(m, v.x), v.y), fmaxf(v.z, v.w));
  }
  for (int o = 32; o; o >>= 1) m = fmaxf(m, __shfl_xor(m, o));
  if (lane == 0) red[wave] = m;
  __syncthreads();
  if (tid == 0) srm = fmaxf(fmaxf(red[0], red[1]), fmaxf(red[2], red[3]));
  __syncthreads();
  float rm = srm;
  float s = 0.f;
  for (int c = tid * 4; c < Vv; c += 1024) {
    f32x4 v = *(const f32x4*)(row + c);
    s += expf(v.x - rm) + expf(v.y - rm) + expf(v.z - rm) + expf(v.w - rm);
    if (v.x >= rm - 0.0625f) { int sl = atomicAdd(&lcnt, 1); if (sl < 32) lcand[sl] = c; }
    if (v.y >= rm - 0.0625f) { int sl = atomicAdd(&lcnt, 1); if (sl < 32) lcand[sl] = c + 1; }
    if (v.z >= rm - 0.0625f) { int sl = atomicAdd(&lcnt, 1); if (sl < 32) lcand[sl] = c + 2; }
    if (v.w >= rm - 0.0625f) { int sl = atomicAdd(&lcnt, 1); if (sl < 32) lcand[sl] = c + 3; }
  }
  for (int o = 32; o; o >>= 1) s += __shfl_xor(s, o);
  if (lane == 0) red[wave] = s;
  __syncthreads();
  if (tid == 0) {
    float st = red[0] + red[1] + red[2] + red[3];
    int cc = lcnt < 32 ? lcnt : 32;
    for (int i = 0; i < cc; i++)                     // sort ascending -> determinism
      for (int k2 = i + 1; k2 < cc; k2++)
        if (lcand[k2] < lcand[i]) { int t = lcand[i]; lcand[i] = lcand[k2]; lcand[k2] = t; }
    rowmax[r] = rm; sumexp[r] = st; ccnt[r] = cc;
    for (int i = 0; i < cc; i++) cand[r * 32 + i] = lcand[i];
  }
}

// ---------------- refine candidates exactly in f32, correct LSE, per-row best ----------------
__global__ __launch_bounds__(256, 1) void k_refine(const float* __restrict__ logits,
    const float* __restrict__ h2f, const float* __restrict__ Wvoc, const float* __restrict__ bvoc,
    const float* __restrict__ rowmax, const float* __restrict__ sumexp,
    const int* __restrict__ ccnt, const int* __restrict__ cand,
    float* __restrict__ lsec, float* __restrict__ bestv, int* __restrict__ besti) {
  int r = blockIdx.x;
  __shared__ float hrow[Hh];
  __shared__ float lex[32];
  __shared__ float del[32];
  int tid = threadIdx.x, wave = tid >> 6, lane = tid & 63;
  for (int k = tid; k < Hh; k += 256) hrow[k] = h2f[(size_t)r * Hh + k];
  int cnt = ccnt[r];
  float rm = rowmax[r];
  __syncthreads();
  for (int ci = wave; ci < cnt; ci += 4) {
    int v = cand[r * 32 + ci];
    const float* wrw = Wvoc + (size_t)v * Hh;
    float s = 0.f;
    for (int k = lane; k < Hh; k += 64) s += hrow[k] * wrw[k];
    for (int o = 32; o; o >>= 1) s += __shfl_xor(s, o);
    if (lane == 0) {
      float le = s + bvoc[v];
      lex[ci] = le;
      float la = logits[(size_t)r * Vv + v];
      del[ci] = expf(le - rm) - expf(la - rm);
    }
  }
  __syncthreads();
  if (tid == 0) {
    float se = sumexp[r];
    for (int i = 0; i < cnt; i++) se += del[i];
    float lse = rm + logf(se);
    lsec[r] = lse;
    float bv = -3.0e38f; int bvi = 0;
    for (int i = 0; i < cnt; i++)
      if (lex[i] > bv) { bv = lex[i]; bvi = cand[r * 32 + i]; }  // sorted -> ties keep lowest v
    bestv[r] = bv - lse;
    besti[r] = (r & 63) * Vv + bvi;                               // flat index b*V + v
  }
}

// ---------------- per-step global argmax -> seq ----------------
__global__ void k_argmax(const float* __restrict__ bestv, const int* __restrict__ besti,
                         float* __restrict__ outseq) {
  int tid = threadIdx.x;                                          // 64 threads (1 wave)
  if (tid == 0) outseq[0] = 1.0f;                                 // BOS
  for (int t = 0; t < Tt; t++) {
    float v = bestv[t * 64 + tid];
    int ii = besti[t * 64 + tid];
    for (int o = 1; o < 64; o <<= 1) {
      float ov = __shfl_xor(v, o);
      int oi = __shfl_xor(ii, o);
      if (ov > v || (ov == v && oi < ii)) { v = ov; ii = oi; }
    }
    if (tid == 0) outseq[1 + t] = (float)ii;
  }
}

// ---------------- in-place log-softmax: logits -= lse[row] ----------------
__global__ __launch_bounds__(256, 2) void k_logp(float* __restrict__ logits,
                                                 const float* __restrict__ lsec) {
  size_t total = (size_t)Tt * Bb * Vv / 4;
  for (size_t p = (size_t)blockIdx.x * 256 + threadIdx.x; p < total;
       p += (size_t)gridDim.x * 256) {
    int r = (int)(p / (Vv / 4));
    f32x4 v = *(f32x4*)(logits + p * 4);
    float l = lsec[r];
    v.x -= l; v.y -= l; v.z -= l; v.w -= l;
    *(f32x4*)(logits + p * 4) = v;
  }
}

// ---------------- host: launch sequence ----------------
extern "C" void kernel_launch(void* const* d_in, const int* in_sizes, int n_in,
                              void* d_out, int out_size, void* d_ws, size_t ws_size,
                              hipStream_t stream) {
  (void)in_sizes; (void)n_in; (void)out_size; (void)ws_size;
  const int*   inp     = (const int*)d_in[0];
  const float* eps     = (const float*)d_in[1];
  const float* emb_enc = (const float*)d_in[2];
  const float* Wih_e   = (const float*)d_in[3];
  const float* Whh_e   = (const float*)d_in[4];
  const float* bih_e   = (const float*)d_in[5];
  const float* bhh_e   = (const float*)d_in[6];
  const float* W_enc   = (const float*)d_in[7];
  const float* b_enc   = (const float*)d_in[8];
  const float* W_loc   = (const float*)d_in[9];
  const float* b_loc   = (const float*)d_in[10];
  const float* W_sc    = (const float*)d_in[11];
  const float* b_sc    = (const float*)d_in[12];
  const float* emb_dec = (const float*)d_in[13];
  const float* W_dec   = (const float*)d_in[14];
  const float* b_dec   = (const float*)d_in[15];
  const float* Wih_d   = (const float*)d_in[16];
  const float* Whh_d   = (const float*)d_in[17];
  const float* bih_d   = (const float*)d_in[18];
  const float* bhh_d   = (const float*)d_in[19];
  const float* W_voc   = (const float*)d_in[20];
  const float* b_voc   = (const float*)d_in[21];

  char* ws = (char*)d_ws;
  u16*   WHHE3 = (u16*)(ws + OFF_WHHE3);
  u16*   WHHD3 = (u16*)(ws + OFF_WHHD3);
  u16*   WIHE3 = (u16*)(ws + OFF_WIHE3);
  u16*   WVOC  = (u16*)(ws + OFF_WVOC);
  u16*   XS    = (u16*)(ws + OFF_XS);
  float* GX    = (float*)(ws + OFF_GX);
  u16*   HA0   = (u16*)(ws + OFF_HA0);
  u16*   HA1   = (u16*)(ws + OFF_HA1);
  float* Hst   = (float*)(ws + OFF_H);
  float* H2F   = (float*)(ws + OFF_H2F);
  u16*   H2B   = (u16*)(ws + OFF_H2B);
  float* GXD   = (float*)(ws + OFF_GXD);
  float* HENC  = (float*)(ws + OFF_HENC);
  float* ZB    = (float*)(ws + OFF_ZB);
  float* RM    = (float*)(ws + OFF_RM);
  float* SE    = (float*)(ws + OFF_SE);
  float* LSE   = (float*)(ws + OFF_LSE);
  float* BV    = (float*)(ws + OFF_BV);
  int*   BI    = (int*)(ws + OFF_BI);
  int*   CC    = (int*)(ws + OFF_CC);
  int*   CAND  = (int*)(ws + OFF_CAND);

  float* out     = (float*)d_out;
  float* logits  = out;                                   // (T*B, V) f32
  float* outseq  = out + (size_t)Tt * Bb * Vv;
  float* outloc  = outseq + (Tt + 1);
  float* outsc   = outloc + Bb * Zz;

  // --- weight conversions ---
  k_trip<<<1024, 256, 0, stream>>>(Whh_e, WHHE3, G3, Hh);
  k_trip<<<1024, 256, 0, stream>>>(Whh_d, WHHD3, G3, Hh);
  k_trip<<<512, 256, 0, stream>>>(Wih_e, WIHE3, G3, Ee);
  k_tobf<<<2048, 256, 0, stream>>>(W_voc, WVOC, Vv * Hh);
  k_xsplit<<<2048, 256, 0, stream>>>(inp, emb_enc, XS);

  // --- gx = x' * Wih_e3^T + bih_e   (M=16384, N=3072, K=1536) ---
  {
    dim3 g(G3 / 128, (Ss * Bb) / 128);
    gemm_bt<<<g, 256, 0, stream>>>(XS, WIHE3, bih_e, GX, Ss * Bb, G3, 3 * Ee);
  }
  // XS dead now; overlay region becomes live.
  k_gxd<<<12, 256, 0, stream>>>(emb_dec, Wih_d, bih_d, GXD);
  k_zero<<<256, 256, 0, stream>>>((u32*)HA0, (int)((2 * (size_t)Bb * G3 * 2 + (size_t)Bb * Hh * 4) / 4));

  // --- encoder: 256 sequential GRU steps ---
  for (int s = 0; s < Ss; s++) {
    const u16* hin = (s & 1) ? HA1 : HA0;
    u16* hout = (s & 1) ? HA0 : HA1;
    k_step<0><<<128, 256, 0, stream>>>(WHHE3, bhh_e, GX + (size_t)s * Bb * G3,
                                       hin, hout, Hst, nullptr, nullptr);
  }

  // --- heads ---
  k_head1<<<64, 256, 0, stream>>>(Hst, W_enc, b_enc, HENC);
  k_head2<<<64, 256, 0, stream>>>(HENC, W_loc, b_loc, W_sc, b_sc, eps, outloc, outsc, ZB);
  k_head3<<<64, 256, 0, stream>>>(ZB, W_dec, b_dec, Hst, HA0);

  // --- decoder: 64 sequential GRU steps ---
  for (int t = 0; t < Tt; t++) {
    const u16* hin = (t & 1) ? HA1 : HA0;
    u16* hout = (t & 1) ? HA0 : HA1;
    k_step<1><<<128, 256, 0, stream>>>(WHHD3, bhh_d, GXD, hin, hout, Hst,
                                       H2F + (size_t)t * Bb * Hh, H2B + (size_t)t * Bb * Hh);
  }

  // --- vocab projection: logits = h2 * Wvoc^T + b_voc  (M=4096, N=32000, K=1024) ---
  {
    dim3 g(Vv / 128, (Tt * Bb) / 128);
    gemm_bt<<<g, 256, 0, stream>>>(H2B, WVOC, b_voc, logits, Tt * Bb, Vv, Hh);
  }

  // --- softmax stats + exact argmax refinement ---
  k_rowred<<<Tt * Bb, 256, 0, stream>>>(logits, RM, SE, CC, CAND);
  k_refine<<<Tt * Bb, 256, 0, stream>>>(logits, H2F, W_voc, b_voc, RM, SE, CC, CAND, LSE, BV, BI);
  k_argmax<<<1, 64, 0, stream>>>(BV, BI, outseq);
  k_logp<<<2048, 256, 0, stream>>>(logits, LSE);
}